// Round 1
// baseline (32.590 us; speedup 1.0000x reference)
//
#include <hip/hip_runtime.h>
#include <math.h>

#define DIM 512
#define ROWS 4      // batch rows per block
#define NJT 256     // j-threads (each owns j=t and j=t+256)
#define NIG 4       // i-interleave groups
#define TPB (NJT * NIG)   // 1024 threads = 16 waves

// logit[b] = W[0:512].x + sum_{i<j} x_i x_j Wp[idx(i,j)] + sum_i x_i^2 Wsq[i] + bias
// Wp row i starts at offset(i) = 511*i - i*(i-1)/2 ; element (i,j) at offset(i)+(j-i-1)

__global__ __launch_bounds__(TPB, 4)
void logistic_quad_kernel(const float* __restrict__ x,
                          const float* __restrict__ W,
                          const float* __restrict__ bias,
                          float* __restrict__ out) {
    const int tid = threadIdx.x;
    const int t   = tid & (NJT - 1);  // j-slot lane
    const int g   = tid >> 8;         // i-group 0..3
    const int row0 = blockIdx.x * ROWS;

    const float* xr0 = x + (size_t)(row0 + 0) * DIM;
    const float* xr1 = x + (size_t)(row0 + 1) * DIM;
    const float* xr2 = x + (size_t)(row0 + 2) * DIM;
    const float* xr3 = x + (size_t)(row0 + 3) * DIM;

    const int j1 = t;
    const int j2 = t + NJT;

    // x values at owned columns (registers for the whole kernel)
    float xj1_0 = xr0[j1], xj2_0 = xr0[j2];
    float xj1_1 = xr1[j1], xj2_1 = xr1[j2];
    float xj1_2 = xr2[j1], xj2_2 = xr2[j2];
    float xj1_3 = xr3[j1], xj2_3 = xr3[j2];

    const float* Wlin = W;
    const float* Wp   = W + DIM;                        // pairs (130816)
    const float* Wsq  = W + DIM + DIM * (DIM - 1) / 2;  // squares

    // Accumulators t_j[r] = sum_i x[r][i] * U[i][j]; fold linear+square into init
    // (only g==0 contributes the init, to avoid 4x counting)
    float t1_0, t1_1, t1_2, t1_3, t2_0, t2_1, t2_2, t2_3;
    if (g == 0) {
        float wl1 = Wlin[j1], wl2 = Wlin[j2];
        float ws1 = Wsq[j1],  ws2 = Wsq[j2];
        t1_0 = fmaf(ws1, xj1_0, wl1); t2_0 = fmaf(ws2, xj2_0, wl2);
        t1_1 = fmaf(ws1, xj1_1, wl1); t2_1 = fmaf(ws2, xj2_1, wl2);
        t1_2 = fmaf(ws1, xj1_2, wl1); t2_2 = fmaf(ws2, xj2_2, wl2);
        t1_3 = fmaf(ws1, xj1_3, wl1); t2_3 = fmaf(ws2, xj2_3, wl2);
    } else {
        t1_0 = t1_1 = t1_2 = t1_3 = 0.f;
        t2_0 = t2_1 = t2_2 = t2_3 = 0.f;
    }

    // Phase A: i in [0,256) step 4 — slot2 unconditional (i < 256 <= j2),
    // slot1 predicated (i < j1); wave-level execz skips past the diagonal.
    #pragma unroll 4
    for (int i = g; i < NJT; i += NIG) {
        const int roff = i * (DIM - 2) - (i * (i - 1)) / 2 - 1;  // offset(i) - i - 1
        const float* rw = Wp + roff;                             // rw[j] = U[i][j], j>i
        float wv1 = rw[j1];   // may be a masked-garbage lane; always in-bounds of W
        float wv2 = rw[j2];
        float xi0 = xr0[i], xi1 = xr1[i], xi2 = xr2[i], xi3 = xr3[i];
        t2_0 = fmaf(xi0, wv2, t2_0);
        t2_1 = fmaf(xi1, wv2, t2_1);
        t2_2 = fmaf(xi2, wv2, t2_2);
        t2_3 = fmaf(xi3, wv2, t2_3);
        if (i < j1) {
            t1_0 = fmaf(xi0, wv1, t1_0);
            t1_1 = fmaf(xi1, wv1, t1_1);
            t1_2 = fmaf(xi2, wv1, t1_2);
            t1_3 = fmaf(xi3, wv1, t1_3);
        }
    }

    // Phase B: i in [256,511) step 4 — slot1 dead, slot2 predicated (i < j2)
    #pragma unroll 4
    for (int i = NJT + g; i < DIM - 1; i += NIG) {
        const int roff = i * (DIM - 2) - (i * (i - 1)) / 2 - 1;
        const float* rw = Wp + roff;
        float wv2 = rw[j2];
        float xi0 = xr0[i], xi1 = xr1[i], xi2 = xr2[i], xi3 = xr3[i];
        if (i < j2) {
            t2_0 = fmaf(xi0, wv2, t2_0);
            t2_1 = fmaf(xi1, wv2, t2_1);
            t2_2 = fmaf(xi2, wv2, t2_2);
            t2_3 = fmaf(xi3, wv2, t2_3);
        }
    }

    // Per-thread partial logits: y[r] = xj1*t1 + xj2*t2 (valid per i-group partials)
    float y0 = xj1_0 * t1_0 + xj2_0 * t2_0;
    float y1 = xj1_1 * t1_1 + xj2_1 * t2_1;
    float y2 = xj1_2 * t1_2 + xj2_2 * t2_2;
    float y3 = xj1_3 * t1_3 + xj2_3 * t2_3;

    // Wave reduction (64 lanes)
    #pragma unroll
    for (int off = 32; off > 0; off >>= 1) {
        y0 += __shfl_down(y0, off);
        y1 += __shfl_down(y1, off);
        y2 += __shfl_down(y2, off);
        y3 += __shfl_down(y3, off);
    }

    __shared__ float red[TPB / 64][ROWS];
    const int wave = tid >> 6;
    const int lane = tid & 63;
    if (lane == 0) {
        red[wave][0] = y0;
        red[wave][1] = y1;
        red[wave][2] = y2;
        red[wave][3] = y3;
    }
    __syncthreads();
    if (tid < ROWS) {
        float z = 0.f;
        #pragma unroll
        for (int w = 0; w < TPB / 64; ++w) z += red[w][tid];
        z += bias[0];
        out[row0 + tid] = 1.0f / (1.0f + expf(-z));
    }
}

extern "C" void kernel_launch(void* const* d_in, const int* in_sizes, int n_in,
                              void* d_out, int out_size, void* d_ws, size_t ws_size,
                              hipStream_t stream) {
    const float* x = (const float*)d_in[0];   // [1024, 512]
    const float* W = (const float*)d_in[1];   // [1, 131840]
    const float* b = (const float*)d_in[2];   // [1]
    float* out = (float*)d_out;               // [1024, 1]

    const int nblocks = 1024 / ROWS;          // 256 blocks, one per CU
    hipLaunchKernelGGL(logistic_quad_kernel, dim3(nblocks), dim3(TPB), 0, stream,
                       x, W, b, out);
}

// Round 2
// 22.933 us; speedup vs baseline: 1.4211x; 1.4211x over previous
//
#include <hip/hip_runtime.h>
#include <math.h>

#define DIM 512
#define BATCH 1024
#define NPAIR (DIM * (DIM - 1) / 2)

#define NCHUNK 4
#define CHUNK (DIM / NCHUNK)   // 128 i's per chunk

// ws layout (floats): M[512*512] at 0 ; partial[NCHUNK][BATCH] at DIM*DIM
#define PART_OFF (DIM * DIM)

// ---------- kernel 1: build dense symmetric M from triangle-packed W ----------
// Wp row i starts at roff(i) = i*(DIM-2) - i(i-1)/2 - 1 ; element (i,j) = Wp[roff(i)+j], j>i
__global__ __launch_bounds__(DIM)
void build_M(const float* __restrict__ W, float* __restrict__ M) {
    const int i = blockIdx.x;
    const int j = threadIdx.x;
    const float* Wp  = W + DIM;
    const float* Wsq = W + DIM + NPAIR;
    if (j > i) {
        const int roff = i * (DIM - 2) - (i * (i - 1)) / 2 - 1;
        const float v = 0.5f * Wp[roff + j];
        M[i * DIM + j] = v;        // coalesced
        M[j * DIM + i] = v;        // scattered store (fire-and-forget)
    } else if (j == i) {
        M[i * DIM + i] = Wsq[i];
    }
}

// ---------- kernel 2: fused t = M x (per chunk) + partial dot y = x.t ----------
#define TPB2 512
#define ROWS 8

__global__ __launch_bounds__(TPB2, 8)
void gemv_quad(const float* __restrict__ x, const float* __restrict__ W,
               const float* __restrict__ M, float* __restrict__ partial) {
    const int rg  = blockIdx.x >> 2;    // row-group 0..127
    const int c   = blockIdx.x & 3;     // i-chunk 0..3
    const int tid = threadIdx.x;
    const int jt  = tid & 127;          // j-quad owner
    const int g   = tid >> 7;           // i-subgroup 0..3 (wave-uniform)
    const int row0 = rg * ROWS;
    const int i0   = c * CHUNK;
    const int j4   = jt * 4;

    // x chunk staged as xs[ii][r], stride 12 floats (48B: 16B-aligned rows)
    __shared__ float xs[CHUNK][12];
    __shared__ float red[TPB2 / 64][ROWS];

    for (int p = tid; p < ROWS * CHUNK; p += TPB2) {
        const int r = p >> 7, ii = p & 127;
        xs[ii][r] = x[(size_t)(row0 + r) * DIM + i0 + ii];
    }
    __syncthreads();

    // acc[r] = t_j quad for row r; fold W_lin into exactly one (c,g) slice
    float4 acc[ROWS];
    if (c == 0 && g == 0) {
        const float4 wl = *(const float4*)(W + j4);
        #pragma unroll
        for (int r = 0; r < ROWS; ++r) acc[r] = wl;
    } else {
        #pragma unroll
        for (int r = 0; r < ROWS; ++r) acc[r] = make_float4(0.f, 0.f, 0.f, 0.f);
    }

    const float* mp = M + (size_t)(i0 + g * 32) * DIM + j4;

    #pragma unroll 2
    for (int it = 0; it < 32; ++it) {
        const float4 w  = *(const float4*)mp;          // coalesced 16B/lane
        const int   ii  = g * 32 + it;
        const float4 xa = *(const float4*)&xs[ii][0];  // broadcast (uniform addr)
        const float4 xb = *(const float4*)&xs[ii][4];
        #define FMA4(A, S) A.x = fmaf(S, w.x, A.x); A.y = fmaf(S, w.y, A.y); \
                           A.z = fmaf(S, w.z, A.z); A.w = fmaf(S, w.w, A.w)
        FMA4(acc[0], xa.x); FMA4(acc[1], xa.y); FMA4(acc[2], xa.z); FMA4(acc[3], xa.w);
        FMA4(acc[4], xb.x); FMA4(acc[5], xb.y); FMA4(acc[6], xb.z); FMA4(acc[7], xb.w);
        #undef FMA4
        mp += DIM;
    }

    // y[r] = sum over this thread's j-quad of x[row][j] * t[row][j]
    float y[ROWS];
    #pragma unroll
    for (int r = 0; r < ROWS; ++r) {
        const float4 xq = *(const float4*)&x[(size_t)(row0 + r) * DIM + j4];
        y[r] = xq.x * acc[r].x + xq.y * acc[r].y + xq.z * acc[r].z + xq.w * acc[r].w;
    }

    // butterfly wave reduction (64 lanes)
    #pragma unroll
    for (int off = 32; off > 0; off >>= 1) {
        #pragma unroll
        for (int r = 0; r < ROWS; ++r) y[r] += __shfl_xor(y[r], off);
    }

    const int wave = tid >> 6, lane = tid & 63;
    if (lane == 0) {
        #pragma unroll
        for (int r = 0; r < ROWS; ++r) red[wave][r] = y[r];
    }
    __syncthreads();
    if (tid < ROWS) {
        float z = 0.f;
        #pragma unroll
        for (int w = 0; w < TPB2 / 64; ++w) z += red[w][tid];
        partial[c * BATCH + row0 + tid] = z;   // deterministic, no atomics
    }
}

// ---------- kernel 3: sum chunk partials + bias, sigmoid ----------
__global__ void finalize(const float* __restrict__ partial, const float* __restrict__ bias,
                         float* __restrict__ out) {
    const int b = blockIdx.x * 256 + threadIdx.x;
    float z = partial[b] + partial[BATCH + b] + partial[2 * BATCH + b] +
              partial[3 * BATCH + b] + bias[0];
    out[b] = 1.0f / (1.0f + expf(-z));
}

extern "C" void kernel_launch(void* const* d_in, const int* in_sizes, int n_in,
                              void* d_out, int out_size, void* d_ws, size_t ws_size,
                              hipStream_t stream) {
    const float* x = (const float*)d_in[0];   // [1024, 512]
    const float* W = (const float*)d_in[1];   // [1, 131840]
    const float* b = (const float*)d_in[2];   // [1]
    float* out = (float*)d_out;               // [1024]

    float* M       = (float*)d_ws;            // 1 MB
    float* partial = (float*)d_ws + PART_OFF; // 16 KB

    hipLaunchKernelGGL(build_M,   dim3(DIM),        dim3(DIM),  0, stream, W, M);
    hipLaunchKernelGGL(gemv_quad, dim3(128 * NCHUNK), dim3(TPB2), 0, stream, x, W, M, partial);
    hipLaunchKernelGGL(finalize,  dim3(BATCH / 256), dim3(256),  0, stream, partial, b, out);
}